// Round 5
// baseline (9272.675 us; speedup 1.0000x reference)
//
#include <hip/hip_runtime.h>

// ---------------------------------------------------------------------------
// MetaRNN (HyperNetwork-conditioned RNN), MI355X gfx950.  v5
//   per layer:
//     1) GEMM (MFMA, split-bf16 x3): xW = x @ Wih^T, xH = x @ Wih_hy_x^T
//     2) scan: 16 blocks x 512 thr (8 waves, 2/SIMD).
//        v5: Whh hi+lo PINNED in regs (128/wave) + zres pinned (32);
//        HY-hi in LDS (96 KB); HY-lo streamed via 4-slot rotation (only
//        vmem inside P1); Wzd streamed early (L2-hot, g0 end-P1, g1/g2
//        after BA); xhv/xwv reloaded immediately AFTER last use so younger
//        HBM loads never block older L2 consumption (vmcnt retires in
//        issue order). 3 raw barriers/step.
//        Split-bf16 3-term products (absmax 0.0039 validated v1-v4).
// ---------------------------------------------------------------------------

#define DEVI __device__ __forceinline__

typedef __bf16 bf16x8 __attribute__((ext_vector_type(8)));
typedef float f32x4 __attribute__((ext_vector_type(4)));
typedef unsigned short u16;
typedef unsigned int u32;
typedef u32 u32x4 __attribute__((ext_vector_type(4)));
typedef u16 u16x8 __attribute__((ext_vector_type(8)));

constexpr int B_ = 256, T_ = 512, D_ = 256, H_ = 256, HH_ = 128, E_ = 32;
constexpr int BT = B_ * T_;

// fragment-buffer offsets (u16 elements), per layer
constexpr int OXW = 0,      PXW = 16 * 8 * 512;   // Wih      [16nt][8kt]
constexpr int OXH = 131072, PXH = 8 * 8 * 512;    // Wih_hy_x [8nt][8kt]
constexpr int OHY = 196608, PHY = 8 * 12 * 512;   // [U_hy|Whh_hy] [8nt][12kt]
constexpr int OWHH = 294912, PWHH = 16 * 8 * 512; // Whh      [16nt][8kt]
constexpr int OWHZ = 425984, PWHZ = 6 * 4 * 512;  // Whz flat [6nt][4kt]
constexpr int OWZD = 450560, PWZD = 48 * 512;     // Wzd      [3g][16nt][1kt]
constexpr int LSTRIDE = 499712;                   // u16 per layer

constexpr size_t WS_XW = 0;
constexpr size_t WS_XH = (size_t)BT * H_ * 4;
constexpr size_t WS_FR = WS_XH + (size_t)BT * HH_ * 4;

DEVI u16 f2bf(float v) {            // round-to-nearest-even fp32 -> bf16 bits
  u32 u = __float_as_uint(v);
  u += 0x7fffu + ((u >> 16) & 1u);
  return (u16)(u >> 16);
}
DEVI float bf2f(u16 s) { return __uint_as_float(((u32)s) << 16); }
DEVI void split2(float v, u16 &hi, u16 &lo) {
  hi = f2bf(v);
  lo = f2bf(v - bf2f(hi));          // exact subtraction
}
DEVI bf16x8 ldfrag(const u16 *p) {
  u32x4 v = *reinterpret_cast<const u32x4 *>(p);
  return __builtin_bit_cast(bf16x8, v);
}
// Pin a fragment in registers (opaque to the optimizer -> no remat/sink).
DEVI void pin(bf16x8 &x) {
  u32x4 t = __builtin_bit_cast(u32x4, x);
  asm volatile("" : "+v"(t));
  x = __builtin_bit_cast(bf16x8, t);
}
DEVI f32x4 mfma3(bf16x8 ah, bf16x8 al, bf16x8 bh, bf16x8 bl, f32x4 c) {
  c = __builtin_amdgcn_mfma_f32_16x16x32_bf16(ah, bh, c, 0, 0, 0);
  c = __builtin_amdgcn_mfma_f32_16x16x32_bf16(ah, bl, c, 0, 0, 0);
  c = __builtin_amdgcn_mfma_f32_16x16x32_bf16(al, bh, c, 0, 0, 0);
  return c;
}
DEVI float tanh_fast(float x) {
  float e = __expf(2.0f * x);       // inf-safe: ->1 / ->-1 at extremes
  return 1.0f - 2.0f / (e + 1.0f);
}
// Raw barrier: LDS ordering enforced (lgkmcnt(0)), vmem loads stay in flight.
DEVI void block_sync() {
  asm volatile("s_waitcnt lgkmcnt(0)\n\ts_barrier" ::: "memory");
}

// ---------------------------------------------------------------------------
// prep: split all weights to bf16 hi/lo and lay out as 16x16x32 B-fragments.
// fragment: element j, lane l  <-  W[nt*16 + (l&15), kt*32 + (l>>4)*8 + j]
// ---------------------------------------------------------------------------
__global__ void metarnn_prep(const float *__restrict__ Wih,
                             const float *__restrict__ Whh,
                             const float *__restrict__ Wih_hy,
                             const float *__restrict__ Whh_hy,
                             const float *__restrict__ Whz,
                             const float *__restrict__ Wzd,
                             u16 *__restrict__ fr) {
  int gid = blockIdx.x * 256 + threadIdx.x;
  int lane = gid & 63;
  int e = gid >> 6;
  if (e >= 2 * 488) return;
  int l = e / 488, r = e - l * 488;
  u16 *base = fr + (size_t)l * LSTRIDE;
  int rowL = lane & 15, kg = (lane >> 4) << 3;

  const float *src = nullptr;
  int ld = 0, nt = 0, kt = 0, KT = 1, special = 0;
  u16 *dh = nullptr, *dl = nullptr;
  if (r < 128) {            // Wih [H,D]
    nt = r >> 3; kt = r & 7; KT = 8;
    src = Wih + (size_t)l * H_ * D_; ld = D_;
    dh = base + OXW; dl = dh + PXW;
  } else if (r < 192) {     // Wih_hy x-part [HH, 0:256]
    r -= 128; nt = r >> 3; kt = r & 7; KT = 8;
    src = Wih_hy + (size_t)l * HH_ * (D_ + H_); ld = D_ + H_;
    dh = base + OXH; dl = dh + PXH;
  } else if (r < 288) {     // concat [U_hy | Whh_hy]  [HH, 384]
    r -= 192; nt = r / 12; kt = r - nt * 12; KT = 12; special = 1;
    dh = base + OHY; dl = dh + PHY;
  } else if (r < 416) {     // Whh [H,H]
    r -= 288; nt = r >> 3; kt = r & 7; KT = 8;
    src = Whh + (size_t)l * H_ * H_; ld = H_;
    dh = base + OWHH; dl = dh + PWHH;
  } else if (r < 440) {     // Whz flat [96, HH]
    r -= 416; nt = r >> 2; kt = r & 3; KT = 4;
    src = Whz + (size_t)l * 3 * E_ * HH_; ld = HH_;
    dh = base + OWHZ; dl = dh + PWHZ;
  } else {                  // Wzd per g: [H, E]
    r -= 440; int g = r >> 4; nt = r & 15; kt = 0; KT = 1;
    src = Wzd + (size_t)(l * 3 + g) * H_ * E_; ld = E_;
    dh = base + OWZD + g * 16 * 512; dl = base + OWZD + PWZD + g * 16 * 512;
  }
  int row = nt * 16 + rowL;
  long dof = ((long)(nt * KT + kt) * 64 + lane) * 8;
  for (int j = 0; j < 8; ++j) {
    int k = kt * 32 + kg + j;
    float v;
    if (special) {
      v = (k < 256) ? Wih_hy[((size_t)l * HH_ + row) * (D_ + H_) + 256 + k]
                    : Whh_hy[((size_t)l * HH_ + row) * HH_ + (k - 256)];
    } else {
      v = src[(size_t)row * ld + k];
    }
    u16 hi, lo;
    split2(v, hi, lo);
    dh[dof + j] = hi;
    dl[dof + j] = lo;
  }
}

// ---------------------------------------------------------------------------
// GEMM: xW[m,0:256], xH[m,0:128] = x[m,0:256] @ {Wih, Wih_hy_x}^T
// ---------------------------------------------------------------------------
__global__ __launch_bounds__(256, 1) void metarnn_gemm(
    const float *__restrict__ x, const u16 *__restrict__ fr,
    float *__restrict__ xW, float *__restrict__ xH) {
  int w = threadIdx.x >> 6, lane = threadIdx.x & 63;
  int m0 = blockIdx.x * 32;
  int rowL = lane & 15, kg = (lane >> 4) << 3;
  f32x4 acc[2][6] = {};
  const u16 *fxw_h = fr + OXW, *fxw_l = fxw_h + PXW;
  const u16 *fxh_h = fr + OXH, *fxh_l = fxh_h + PXH;

  for (int kt = 0; kt < 8; ++kt) {
    bf16x8 ah[2], al[2];
    for (int s = 0; s < 2; ++s) {
      const float *xp = x + (size_t)(m0 + s * 16 + rowL) * 256 + kt * 32 + kg;
      u16x8 vh, vl;
#pragma unroll
      for (int j = 0; j < 8; ++j) {
        u16 hi, lo;
        split2(xp[j], hi, lo);
        vh[j] = hi; vl[j] = lo;
      }
      ah[s] = __builtin_bit_cast(bf16x8, vh);
      al[s] = __builtin_bit_cast(bf16x8, vl);
    }
#pragma unroll
    for (int q = 0; q < 6; ++q) {
      int nt = w * 6 + q;
      long o = (nt < 16) ? ((long)(nt * 8 + kt) * 64 + lane) * 8
                         : ((long)((nt - 16) * 8 + kt) * 64 + lane) * 8;
      const u16 *bh = (nt < 16) ? fxw_h + o : fxh_h + o;
      const u16 *bl = (nt < 16) ? fxw_l + o : fxh_l + o;
      bf16x8 B0 = ldfrag(bh), B1 = ldfrag(bl);
      acc[0][q] = mfma3(ah[0], al[0], B0, B1, acc[0][q]);
      acc[1][q] = mfma3(ah[1], al[1], B0, B1, acc[1][q]);
    }
  }
  for (int s = 0; s < 2; ++s)
    for (int q = 0; q < 6; ++q) {
      int nt = w * 6 + q;
#pragma unroll
      for (int r = 0; r < 4; ++r) {
        int row = m0 + s * 16 + (lane >> 4) * 4 + r;
        if (nt < 16)
          xW[(size_t)row * H_ + nt * 16 + rowL] = acc[s][q][r];
        else
          xH[(size_t)row * HH_ + (nt - 16) * 16 + rowL] = acc[s][q][r];
      }
    }
}

// ---------------------------------------------------------------------------
// scan v5: 16 blocks x 512 threads (8 waves, 2/SIMD). Wave w owns:
//   Whh tiles 2w,2w+1 (hi+lo PINNED, 128 regs), HY tile w (hi LDS, lo
//   4-slot streamed), z tile w (PINNED, w<6), d tiles g x {2w,2w+1}
//   (streamed early, L2-hot).
// Per step: P1(aA,aW) [+D-g0 issue] P2(hh; xhv reload) | BA | [D-g1g2 issue]
//           P3 z | BB | P5 d&arg (xwv reload mid) P6 h | BC
// ---------------------------------------------------------------------------
__global__ __launch_bounds__(512, 2) void metarnn_scan(
    const float *__restrict__ xW, const float *__restrict__ xH,
    const u16 *__restrict__ fr, const float *__restrict__ bmain,
    const float *__restrict__ bhy, const float *__restrict__ bz,
    float *__restrict__ y, float *__restrict__ hlast, int layer, int isLast) {
  __shared__ __align__(16) u16 hc_h[8 * 512];        // h frags kt0..7
  __shared__ __align__(16) u16 hc_l[8 * 512];
  __shared__ __align__(16) u16 hhb_h[2][4 * 512];    // hh frags, t-parity dbuf
  __shared__ __align__(16) u16 hhb_l[2][4 * 512];
  __shared__ __align__(16) u16 zf_h[3 * 512];
  __shared__ __align__(16) u16 zf_l[3 * 512];
  __shared__ __align__(16) u16 hy_lds[8 * 12 * 512]; // HY-hi, 96 KB

  int tid = threadIdx.x, w = tid >> 6, lane = tid & 63;
  int bs = blockIdx.x * 16;
  int rowL = lane & 15, colG = lane >> 4;

  const u16 *FHY = fr + OHY, *FHYl = FHY + PHY;
  const u16 *FWH = fr + OWHH, *FWHl = FWH + PWHH;
  const u16 *FWZ = fr + OWHZ, *FWZl = FWZ + PWHZ;
  const u16 *FZD = fr + OWZD, *FZDl = FZD + PWZD;

  for (int i = tid; i < 8 * 512; i += 512) { hc_h[i] = 0; hc_l[i] = 0; }
  for (int i = tid; i < 4 * 512; i += 512) {
    hhb_h[0][i] = 0; hhb_l[0][i] = 0; hhb_h[1][i] = 0; hhb_l[1][i] = 0;
  }
  for (int i = tid; i < 3 * 512; i += 512) { zf_h[i] = 0; zf_l[i] = 0; }
  // HY-hi -> LDS (once)
  for (int i = tid; i < 8 * 12 * 512 / 8; i += 512) {
    *reinterpret_cast<u32x4 *>(&hy_lds[(size_t)i * 8]) =
        *reinterpret_cast<const u32x4 *>(FHY + (size_t)i * 8);
  }

  // ---- PINNED register-resident weights: Whh hi+lo (128), Whz (32) --------
  bf16x8 RWH[2][8], RWL[2][8];
#pragma unroll
  for (int p = 0; p < 2; ++p)
#pragma unroll
    for (int kt = 0; kt < 8; ++kt) {
      long o = ((long)((2 * w + p) * 8 + kt) * 64 + lane) * 8;
      RWH[p][kt] = ldfrag(FWH + o);  pin(RWH[p][kt]);
      RWL[p][kt] = ldfrag(FWHl + o); pin(RWL[p][kt]);
    }
  bf16x8 zresH[4], zresL[4];
  {
    int wz = (w < 6) ? w : 0;
#pragma unroll
    for (int kk = 0; kk < 4; ++kk) {
      long o = ((long)(wz * 4 + kk) * 64 + lane) * 8;
      zresH[kk] = ldfrag(FWZ + o);  pin(zresH[kk]);
      zresL[kk] = ldfrag(FWZl + o); pin(zresL[kk]);
    }
  }

  // ---- hoisted biases -----------------------------------------------------
  int c2 = 16 * w + rowL;                       // hyper col (0..127)
  float bhv = bhy[layer * HH_ + c2];
  float bzv = (w < 6) ? bz[layer * 3 * E_ + c2] : 0.0f;
  float bbv[2];
  bbv[0] = bmain[layer * H_ + 32 * w + rowL];
  bbv[1] = bmain[layer * H_ + 32 * w + 16 + rowL];

  // ---- HY-lo 4-slot rotating buffer (only vmem inside P1) -----------------
  bf16x8 bYL[4];
#define LOAD_Y(PTR, S, KT)                                                    \
  bYL[S] = ldfrag((PTR) + ((long)(w * 12 + (KT)) * 64 + lane) * 8);
#pragma unroll
  for (int s = 0; s < 4; ++s) { LOAD_Y(FHYl, s, s) }

  // ---- prologue xhv/xwv (t=0) --------------------------------------------
  float xhv[4], xwv[2][4];
#pragma unroll
  for (int r = 0; r < 4; ++r) {
    size_t row = (size_t)(bs + 4 * colG + r) * T_;
    xhv[r] = xH[row * HH_ + c2];
    xwv[0][r] = xW[row * H_ + 32 * w + rowL];
    xwv[1][r] = xW[row * H_ + 32 * w + 16 + rowL];
  }

  __syncthreads();                        // once; full drain acceptable here

  for (int t = 0; t < T_; ++t) {
    const int pr = t & 1;
    // opaque per-iteration base pointers: keeps streamed loads in-loop,
    // placed exactly where written (defeats LICM / remat-sink).
    const u16 *fhyl = FHYl, *fzd = FZD, *fzdl = FZDl;
    asm volatile("" : "+s"(fhyl), "+s"(fzd), "+s"(fzdl));

    // ---- P1: aA (hcat @ HY^T tile w), aW (h @ Whh^T tiles 2w,2w+1) --------
    f32x4 aAe = {}, aAo = {}, aW0 = {}, aW1 = {};
    __builtin_amdgcn_s_setprio(1);
#pragma unroll
    for (int j = 0; j < 12; ++j) {
      const int s4 = j & 3;
      bf16x8 ah, al;
      if (j < 8) {
        ah = ldfrag(&hc_h[j * 512 + lane * 8]);
        al = ldfrag(&hc_l[j * 512 + lane * 8]);
      } else {
        ah = ldfrag(&hhb_h[pr ^ 1][(j - 8) * 512 + lane * 8]);
        al = ldfrag(&hhb_l[pr ^ 1][(j - 8) * 512 + lane * 8]);
      }
      bf16x8 yh = ldfrag(&hy_lds[(w * 12 + j) * 512 + lane * 8]);
      if (j & 1) aAo = mfma3(ah, al, yh, bYL[s4], aAo);
      else       aAe = mfma3(ah, al, yh, bYL[s4], aAe);
      if (j < 8) {
        aW0 = mfma3(ah, al, RWH[0][j], RWL[0][j], aW0);
        aW1 = mfma3(ah, al, RWH[1][j], RWL[1][j], aW1);
        LOAD_Y(fhyl, s4, j + 4)           // prefetch kt=j+4 (distance 4)
      } else {
        LOAD_Y(fhyl, s4, j - 8)           // refill kt 0..3 for t+1
      }
    }
    __builtin_amdgcn_s_setprio(0);
    f32x4 aA;
#pragma unroll
    for (int r = 0; r < 4; ++r) aA[r] = aAe[r] + aAo[r];

    // ---- issue Wzd g0 (consumed at P5, ~1200 cyc away) --------------------
    bf16x8 D0h[2], D0l[2];
#pragma unroll
    for (int p = 0; p < 2; ++p) {
      long o = ((long)(2 * w + p) * 64 + lane) * 8;   // g=0
      D0h[p] = ldfrag(fzd + o);
      D0l[p] = ldfrag(fzdl + o);
    }

    // ---- P2: hh_new = tanh(aA + xH + b_hy) -> hhb[pr]; then reload xhv ----
    {
      int kfr = w >> 1;
      int hb2 = 2 * (w & 1) + (rowL >> 3);
      int j7 = rowL & 7;
#pragma unroll
      for (int r = 0; r < 4; ++r) {
        float v = tanh_fast(aA[r] + xhv[r] + bhv);
        u16 hi, lo;
        split2(v, hi, lo);
        int di = kfr * 512 + ((4 * colG + r) + 16 * hb2) * 8 + j7;
        hhb_h[pr][di] = hi;
        hhb_l[pr][di] = lo;
      }
    }
#pragma unroll
    for (int r = 0; r < 4; ++r) {   // xhv for t+1 (t=T-1: reads scratch, ok)
      xhv[r] = xH[((size_t)(bs + 4 * colG + r) * T_ + t + 1) * HH_ + c2];
    }
    block_sync();                          // BA (hh(t) frags visible)

    // ---- issue Wzd g1,g2 (consumed at P5, ~500+ cyc away) -----------------
    bf16x8 D1h[2], D1l[2], D2h[2], D2l[2];
#pragma unroll
    for (int p = 0; p < 2; ++p) {
      long o1 = ((long)(16 + 2 * w + p) * 64 + lane) * 8;   // g=1
      long o2 = ((long)(32 + 2 * w + p) * 64 + lane) * 8;   // g=2
      D1h[p] = ldfrag(fzd + o1);
      D1l[p] = ldfrag(fzdl + o1);
      D2h[p] = ldfrag(fzd + o2);
      D2l[p] = ldfrag(fzdl + o2);
    }

    // ---- P3/P4: z = hh_new @ Whz^T + bz -> zf frags (waves 0..5) ----------
    if (w < 6) {
      f32x4 aZ = {};
#pragma unroll
      for (int kk = 0; kk < 4; ++kk) {
        bf16x8 ah = ldfrag(&hhb_h[pr][kk * 512 + lane * 8]);
        bf16x8 al = ldfrag(&hhb_l[pr][kk * 512 + lane * 8]);
        aZ = mfma3(ah, al, zresH[kk], zresL[kk], aZ);
      }
      int g = c2 >> 5;                     // c2 = 16w+rowL in [0,96)
      int hb3 = 2 * (w & 1) + (rowL >> 3);
      int j7 = rowL & 7;
#pragma unroll
      for (int r = 0; r < 4; ++r) {
        float v = aZ[r] + bzv;
        u16 hi, lo;
        split2(v, hi, lo);
        int di = g * 512 + ((4 * colG + r) + 16 * hb3) * 8 + j7;
        zf_h[di] = hi;
        zf_l[di] = lo;
      }
    }
    block_sync();                          // BB (zf ready)

    // ---- P5: d_g = z @ Wzd_g^T, accumulate h-arg over g (order g=0,1,2) ---
    float arg[2][4];
#pragma unroll
    for (int p = 0; p < 2; ++p)
#pragma unroll
      for (int r = 0; r < 4; ++r) arg[p][r] = bbv[p];
    {
      bf16x8 zh = ldfrag(&zf_h[0 * 512 + lane * 8]);
      bf16x8 zl = ldfrag(&zf_l[0 * 512 + lane * 8]);
#pragma unroll
      for (int p = 0; p < 2; ++p) {
        f32x4 zero = {};
        f32x4 dg = mfma3(zh, zl, D0h[p], D0l[p], zero);
#pragma unroll
        for (int r = 0; r < 4; ++r) arg[p][r] += dg[r] * xwv[p][r];
      }
    }
#pragma unroll
    for (int r = 0; r < 4; ++r) {   // xwv for t+1 (after last use)
      size_t row = (size_t)(bs + 4 * colG + r) * T_ + t + 1;
      xwv[0][r] = xW[row * H_ + 32 * w + rowL];
      xwv[1][r] = xW[row * H_ + 32 * w + 16 + rowL];
    }
    {
      bf16x8 zh = ldfrag(&zf_h[1 * 512 + lane * 8]);
      bf16x8 zl = ldfrag(&zf_l[1 * 512 + lane * 8]);
#pragma unroll
      for (int p = 0; p < 2; ++p) {
        f32x4 zero = {};
        f32x4 dg = mfma3(zh, zl, D1h[p], D1l[p], zero);
#pragma unroll
        for (int r = 0; r < 4; ++r)
          arg[p][r] += dg[r] * ((p == 0) ? aW0[r] : aW1[r]);
      }
    }
    {
      bf16x8 zh = ldfrag(&zf_h[2 * 512 + lane * 8]);
      bf16x8 zl = ldfrag(&zf_l[2 * 512 + lane * 8]);
#pragma unroll
      for (int p = 0; p < 2; ++p) {
        f32x4 zero = {};
        f32x4 dg = mfma3(zh, zl, D2h[p], D2l[p], zero);
#pragma unroll
        for (int r = 0; r < 4; ++r) arg[p][r] += dg[r];
      }
    }

    // ---- P6: h_new = tanh(arg), write y, refresh hc frags -----------------
#pragma unroll
    for (int p = 0; p < 2; ++p) {
      int c = 32 * w + 16 * p + rowL;
      int hb6 = 2 * p + (rowL >> 3);
      int j7 = rowL & 7;
#pragma unroll
      for (int r = 0; r < 4; ++r) {
        int m = 4 * colG + r;
        float h = tanh_fast(arg[p][r]);
        size_t gi = (size_t)(bs + m) * T_ + t;
        y[gi * H_ + c] = h;
        if (isLast && t == T_ - 1) hlast[(size_t)(bs + m) * H_ + c] = h;
        u16 hi, lo;
        split2(h, hi, lo);
        int di = (c >> 5) * 512 + (m + 16 * hb6) * 8 + j7;
        hc_h[di] = hi;
        hc_l[di] = lo;
      }
    }
    block_sync();                          // BC (h(t) frags ready for P1(t+1))
  }
#undef LOAD_Y
}

// ---------------------------------------------------------------------------
extern "C" void kernel_launch(void *const *d_in, const int *in_sizes, int n_in,
                              void *d_out, int out_size, void *d_ws,
                              size_t ws_size, hipStream_t stream) {
  (void)in_sizes; (void)n_in; (void)out_size; (void)ws_size;
  const float *input  = (const float *)d_in[0];
  const float *Wih    = (const float *)d_in[1];
  const float *Whh    = (const float *)d_in[2];
  const float *b      = (const float *)d_in[3];
  const float *Wih_hy = (const float *)d_in[4];
  const float *Whh_hy = (const float *)d_in[5];
  const float *b_hy   = (const float *)d_in[6];
  const float *Whz    = (const float *)d_in[7];
  const float *bz     = (const float *)d_in[8];
  const float *Wzd    = (const float *)d_in[9];

  float *out = (float *)d_out;
  float *xW = (float *)((char *)d_ws + WS_XW);
  float *xH = (float *)((char *)d_ws + WS_XH);
  u16 *fr = (u16 *)((char *)d_ws + WS_FR);
  float *hlast = out + (size_t)BT * H_;

  metarnn_prep<<<dim3(244), dim3(256), 0, stream>>>(Wih, Whh, Wih_hy, Whh_hy,
                                                    Whz, Wzd, fr);
  for (int l = 0; l < 2; ++l) {
    const float *xsrc = (l == 0) ? input : out;   // layer1 reads layer0 output
    const u16 *frl = fr + (size_t)l * LSTRIDE;
    metarnn_gemm<<<dim3(BT / 32), dim3(256), 0, stream>>>(xsrc, frl, xW, xH);
    metarnn_scan<<<dim3(16), dim3(512), 0, stream>>>(
        xW, xH, frl, b, b_hy, bz, out, hlast, l, (l == 1) ? 1 : 0);
  }
}